// Round 1
// baseline (1017.275 us; speedup 1.0000x reference)
//
#include <hip/hip_runtime.h>
#include <cstdint>

#define CDIM 40
#define FDIM 128

// ---- index helpers: edge_index may be int32 or int64; detected at runtime ----
static __device__ __forceinline__ long long load_idx(const void* p, int is64, long long i) {
    if (is64) return ((const long long*)p)[i];
    return (long long)((const int*)p)[i];
}

// Detect int64 storage: little-endian int64 values < 2^31 have all odd 32-bit
// words == 0. Genuine int32 node ids (uniform [0,100000)) make this impossible
// over 1024 samples.
__global__ void k_detect(const unsigned int* w, int nscan, int* flag) {
    if (blockIdx.x == 0 && threadIdx.x == 0) {
        int is64 = 1;
        for (int k = 1; k < nscan; k += 2) {
            if (w[k] != 0u) { is64 = 0; break; }
        }
        *flag = is64;
    }
}

__global__ void k_fill1(float* deg, int N) {
    int i = blockIdx.x * blockDim.x + threadIdx.x;
    if (i < N) deg[i] = 1.0f;
}

__global__ void k_count(const void* ei, const int* flag, long long E, float* deg) {
    long long e = (long long)blockIdx.x * blockDim.x + threadIdx.x;
    if (e >= E) return;
    int is64 = *flag;
    long long d = load_idx(ei, is64, E + e);   // row 1 = dst
    atomicAdd(&deg[d], 1.0f);
}

__global__ void k_rsqrt(float* deg, int N) {
    int i = blockIdx.x * blockDim.x + threadIdx.x;
    if (i < N) deg[i] = rsqrtf(deg[i]);
}

// y[i,c] = sum_f x[i,f] * W[c,f]   (N x 40, F=128)
__global__ void k_gemm(const float* __restrict__ x, const float* __restrict__ W,
                       float* __restrict__ y, int N) {
    unsigned gid = blockIdx.x * blockDim.x + threadIdx.x;
    if (gid >= (unsigned)N * CDIM) return;
    unsigned i = gid / CDIM;
    unsigned c = gid - i * CDIM;
    const float4* xr = (const float4*)(x + (size_t)i * FDIM);
    const float4* wr = (const float4*)(W + (size_t)c * FDIM);
    float acc = 0.0f;
#pragma unroll
    for (int f = 0; f < FDIM / 4; ++f) {
        float4 a = xr[f];
        float4 w4 = wr[f];
        acc += a.x * w4.x + a.y * w4.y + a.z * w4.z + a.w * w4.w;
    }
    y[gid] = acc;
}

// h_out[i,c] = dinv[i]^2 * h_in[i,c] (+ b[c] on final hop). Fully writes h_out.
__global__ void k_selfloop(const float* __restrict__ hin, const float* __restrict__ dinv,
                           const float* __restrict__ b, float* __restrict__ hout,
                           int N, int addBias) {
    unsigned gid = blockIdx.x * blockDim.x + threadIdx.x;
    if (gid >= (unsigned)N * CDIM) return;
    unsigned i = gid / CDIM;
    unsigned c = gid - i * CDIM;
    float d = dinv[i];
    float v = d * d * hin[gid];
    if (addBias) v += b[c];
    hout[gid] = v;
}

// one thread per (edge, channel): h_out[dst,c] += dinv[src]*dinv[dst]*h_in[src,c]
__global__ void k_scatter(const void* ei, const int* flag, long long E,
                          const float* __restrict__ dinv,
                          const float* __restrict__ hin, float* hout) {
    unsigned gid = blockIdx.x * blockDim.x + threadIdx.x;
    unsigned total = (unsigned)(E * CDIM);
    if (gid >= total) return;
    unsigned e = gid / CDIM;
    unsigned c = gid - e * CDIM;
    int is64 = *flag;
    long long s = load_idx(ei, is64, e);
    long long d = load_idx(ei, is64, E + e);
    float nrm = dinv[s] * dinv[d];
    atomicAdd(&hout[(size_t)d * CDIM + c], nrm * hin[(size_t)s * CDIM + c]);
}

extern "C" void kernel_launch(void* const* d_in, const int* in_sizes, int n_in,
                              void* d_out, int out_size, void* d_ws, size_t ws_size,
                              hipStream_t stream) {
    const float* x  = (const float*)d_in[0];
    const void*  ei = d_in[1];
    const float* W  = (const float*)d_in[2];
    const float* b  = (const float*)d_in[3];
    float* out = (float*)d_out;

    const int N = in_sizes[0] / FDIM;            // 100000
    const long long E = (long long)in_sizes[1] / 2;  // 1600000

    // workspace layout: [flag(256B)] [dinv: N floats] [y: N*C] [h1: N*C]
    char* wsb = (char*)d_ws;
    int*   flag = (int*)wsb;
    float* dinv = (float*)(wsb + 256);
    float* y    = dinv + N;
    float* h1   = y + (size_t)N * CDIM;

    const int B = 256;
    const int nbN  = (N + B - 1) / B;
    const unsigned NC = (unsigned)N * CDIM;
    const int nbNC = (int)((NC + B - 1) / B);
    const int nbE  = (int)((E + B - 1) / B);
    const unsigned EC = (unsigned)(E * CDIM);
    const int nbEC = (int)((EC + B - 1) / B);

    int nscan = (int)((2 * E < 2048) ? (2 * E) : 2048);

    k_detect  <<<1, 1, 0, stream>>>((const unsigned int*)ei, nscan, flag);
    k_fill1   <<<nbN, B, 0, stream>>>(dinv, N);
    k_count   <<<nbE, B, 0, stream>>>(ei, flag, E, dinv);
    k_rsqrt   <<<nbN, B, 0, stream>>>(dinv, N);
    k_gemm    <<<nbNC, B, 0, stream>>>(x, W, y, N);

    // hop 1: y -> h1
    k_selfloop<<<nbNC, B, 0, stream>>>(y, dinv, b, h1, N, 0);
    k_scatter <<<nbEC, B, 0, stream>>>(ei, flag, E, dinv, y, h1);

    // hop 2: h1 -> out (+bias)
    k_selfloop<<<nbNC, B, 0, stream>>>(h1, dinv, b, out, N, 1);
    k_scatter <<<nbEC, B, 0, stream>>>(ei, flag, E, dinv, h1, out);
}

// Round 2
// 380.836 us; speedup vs baseline: 2.6712x; 2.6712x over previous
//
#include <hip/hip_runtime.h>
#include <cstdint>

#define CDIM 40
#define C4 10          // CDIM/4 float4 groups
#define FDIM 128
#define SCAN_T 256
#define SCAN_E 1024    // elements per scan block

static __device__ __forceinline__ long long load_idx(const void* p, int is64, long long i) {
    if (is64) return ((const long long*)p)[i];
    return (long long)((const int*)p)[i];
}

// Detect int64 storage: little-endian int64 values < 2^31 have all odd 32-bit
// words == 0; impossible for 1024 genuine int32 node ids.
__global__ void k_detect(const unsigned int* w, int nscan, int* flag) {
    if (blockIdx.x == 0 && threadIdx.x == 0) {
        int is64 = 1;
        for (int k = 1; k < nscan; k += 2) {
            if (w[k] != 0u) { is64 = 0; break; }
        }
        *flag = is64;
    }
}

__global__ void k_zero(int* p, int n) {
    int i = blockIdx.x * blockDim.x + threadIdx.x;
    if (i < n) p[i] = 0;
}

__global__ void k_hist(const void* ei, const int* flag, long long E, int* cnt) {
    long long e = (long long)blockIdx.x * blockDim.x + threadIdx.x;
    if (e >= E) return;
    int is64 = *flag;
    long long d = load_idx(ei, is64, E + e);
    atomicAdd(&cnt[d], 1);
}

// Per-block exclusive scan of 1024 elements; writes per-element exclusive
// prefix (within block) to row_ptr, block total to bsum.
__global__ void k_scan1(const int* __restrict__ cnt, int N, int* __restrict__ row_ptr,
                        int* __restrict__ bsum) {
    __shared__ int ls[SCAN_T];
    int tid = threadIdx.x;
    int base = blockIdx.x * SCAN_E;
    int v[4], loc = 0;
#pragma unroll
    for (int k = 0; k < 4; ++k) {
        int idx = base + tid * 4 + k;
        v[k] = (idx < N) ? cnt[idx] : 0;
        loc += v[k];
    }
    ls[tid] = loc;
    __syncthreads();
    for (int off = 1; off < SCAN_T; off <<= 1) {
        int t = (tid >= off) ? ls[tid - off] : 0;
        __syncthreads();
        ls[tid] += t;
        __syncthreads();
    }
    int excl = ls[tid] - loc;
    if (tid == SCAN_T - 1) bsum[blockIdx.x] = ls[SCAN_T - 1];
    int run = excl;
#pragma unroll
    for (int k = 0; k < 4; ++k) {
        int idx = base + tid * 4 + k;
        if (idx < N) row_ptr[idx] = run;
        run += v[k];
    }
}

// Single-block exclusive scan (in place) of up to 1024 block sums.
__global__ void k_scan2(int* bsum, int nb) {
    __shared__ int ls[SCAN_T];
    int tid = threadIdx.x;
    int v[4], loc = 0;
#pragma unroll
    for (int k = 0; k < 4; ++k) {
        int idx = tid * 4 + k;
        v[k] = (idx < nb) ? bsum[idx] : 0;
        loc += v[k];
    }
    ls[tid] = loc;
    __syncthreads();
    for (int off = 1; off < SCAN_T; off <<= 1) {
        int t = (tid >= off) ? ls[tid - off] : 0;
        __syncthreads();
        ls[tid] += t;
        __syncthreads();
    }
    int excl = ls[tid] - loc;
    int run = excl;
#pragma unroll
    for (int k = 0; k < 4; ++k) {
        int idx = tid * 4 + k;
        if (idx < nb) bsum[idx] = run;
        run += v[k];
    }
}

// Finalize: row_ptr += block prefix; cursor = row_ptr; dinv = rsqrt(1+cnt)
__global__ void k_scan3(int* __restrict__ row_ptr, const int* __restrict__ bsum,
                        int* __restrict__ cursor, const int* __restrict__ cnt,
                        float* __restrict__ dinv, int N) {
    int i = blockIdx.x * blockDim.x + threadIdx.x;
    if (i >= N) return;
    int rp = row_ptr[i] + bsum[i >> 10];
    row_ptr[i] = rp;
    cursor[i] = rp;
    dinv[i] = rsqrtf(1.0f + (float)cnt[i]);
}

// Scatter edges into CSR slots: csr[pos] = {src, norm}
__global__ void k_reorder(const void* ei, const int* flag, long long E,
                          int* __restrict__ cursor, const float* __restrict__ dinv,
                          int2* __restrict__ csr) {
    long long e = (long long)blockIdx.x * blockDim.x + threadIdx.x;
    if (e >= E) return;
    int is64 = *flag;
    int s = (int)load_idx(ei, is64, e);
    int d = (int)load_idx(ei, is64, E + e);
    int pos = atomicAdd(&cursor[d], 1);
    float nrm = dinv[s] * dinv[d];
    csr[pos] = make_int2(s, __float_as_int(nrm));
}

// y[i,c] = sum_f x[i,f]*W[c,f]. Thread per (i, c4): 4 channels, W^T in LDS.
__global__ void k_gemm(const float* __restrict__ x, const float* __restrict__ W,
                       float* __restrict__ y, int N) {
    __shared__ float wt[FDIM * CDIM];  // layout [f][c], 20 KiB
    int tid = threadIdx.x;
    for (int idx = tid; idx < FDIM * CDIM; idx += 256) {
        int c = idx / FDIM, f = idx - c * FDIM;
        wt[f * CDIM + c] = W[idx];
    }
    __syncthreads();
    unsigned gid = blockIdx.x * 256 + tid;
    if (gid >= (unsigned)N * C4) return;
    unsigned i = gid / C4;
    unsigned cg = gid - i * C4;
    const float4* x4 = (const float4*)x + (size_t)i * (FDIM / 4);
    float4 acc = make_float4(0.f, 0.f, 0.f, 0.f);
#pragma unroll
    for (int f4 = 0; f4 < FDIM / 4; ++f4) {
        float4 xv = x4[f4];
        float xa[4] = {xv.x, xv.y, xv.z, xv.w};
#pragma unroll
        for (int k = 0; k < 4; ++k) {
            const float4 wv = *(const float4*)&wt[(4 * f4 + k) * CDIM + cg * 4];
            acc.x += xa[k] * wv.x;
            acc.y += xa[k] * wv.y;
            acc.z += xa[k] * wv.z;
            acc.w += xa[k] * wv.w;
        }
    }
    ((float4*)y)[gid] = acc;
}

// One hop: hout[i,:] = dinv[i]^2*hin[i,:] + sum_in-edges norm*hin[src,:] (+b)
__global__ void k_gather(const int* __restrict__ row_ptr, const int* __restrict__ cnt,
                         const int2* __restrict__ csr, const float* __restrict__ dinv,
                         const float* __restrict__ hin, const float* __restrict__ b,
                         float* __restrict__ hout, int N, int addBias) {
    unsigned gid = blockIdx.x * blockDim.x + threadIdx.x;
    if (gid >= (unsigned)N * C4) return;
    unsigned i = gid / C4;
    unsigned cg = gid - i * C4;
    const float4* h4 = (const float4*)hin;
    float di = dinv[i];
    float4 hv = h4[(size_t)i * C4 + cg];
    float s2 = di * di;
    float4 acc = make_float4(s2 * hv.x, s2 * hv.y, s2 * hv.z, s2 * hv.w);
    int beg = row_ptr[i];
    int end = beg + cnt[i];
    for (int j = beg; j < end; ++j) {
        int2 e = csr[j];
        float w = __int_as_float(e.y);
        float4 v = h4[(size_t)e.x * C4 + cg];
        acc.x += w * v.x;
        acc.y += w * v.y;
        acc.z += w * v.z;
        acc.w += w * v.w;
    }
    if (addBias) {
        float4 bv = ((const float4*)b)[cg];
        acc.x += bv.x; acc.y += bv.y; acc.z += bv.z; acc.w += bv.w;
    }
    ((float4*)hout)[gid] = acc;
}

static inline size_t align256(size_t v) { return (v + 255) & ~(size_t)255; }

extern "C" void kernel_launch(void* const* d_in, const int* in_sizes, int n_in,
                              void* d_out, int out_size, void* d_ws, size_t ws_size,
                              hipStream_t stream) {
    const float* x  = (const float*)d_in[0];
    const void*  ei = d_in[1];
    const float* W  = (const float*)d_in[2];
    const float* b  = (const float*)d_in[3];
    float* out = (float*)d_out;

    const int N = in_sizes[0] / FDIM;                 // 100000
    const long long E = (long long)in_sizes[1] / 2;   // 1600000

    // workspace layout (256B aligned chunks)
    char* wsb = (char*)d_ws;
    size_t off = 0;
    int*   flag   = (int*)(wsb + off);  off = align256(off + 4);
    int*   cnt    = (int*)(wsb + off);  off = align256(off + (size_t)N * 4);
    int*   rowp   = (int*)(wsb + off);  off = align256(off + (size_t)N * 4);
    int*   cursor = (int*)(wsb + off);  off = align256(off + (size_t)N * 4);
    int*   bsum   = (int*)(wsb + off);  off = align256(off + 1024 * 4);
    float* dinv   = (float*)(wsb + off); off = align256(off + (size_t)N * 4);
    float* y      = (float*)(wsb + off); off = align256(off + (size_t)N * CDIM * 4);
    float* h1     = (float*)(wsb + off); off = align256(off + (size_t)N * CDIM * 4);
    int2*  csr    = (int2*)(wsb + off);  off = align256(off + (size_t)E * 8);

    const int B = 256;
    const int nbN   = (N + B - 1) / B;
    const int nbE   = (int)((E + B - 1) / B);
    const unsigned NT = (unsigned)N * C4;             // 1M threads
    const int nbNT  = (int)((NT + B - 1) / B);
    const int nb1   = (N + SCAN_E - 1) / SCAN_E;      // 98 scan blocks

    int nscan = (int)((2 * E < 2048) ? (2 * E) : 2048);

    k_detect <<<1, 1, 0, stream>>>((const unsigned int*)ei, nscan, flag);
    k_zero   <<<nbN, B, 0, stream>>>(cnt, N);
    k_hist   <<<nbE, B, 0, stream>>>(ei, flag, E, cnt);
    k_scan1  <<<nb1, SCAN_T, 0, stream>>>(cnt, N, rowp, bsum);
    k_scan2  <<<1, SCAN_T, 0, stream>>>(bsum, nb1);
    k_scan3  <<<nbN, B, 0, stream>>>(rowp, bsum, cursor, cnt, dinv, N);
    k_reorder<<<nbE, B, 0, stream>>>(ei, flag, E, cursor, dinv, csr);
    k_gemm   <<<nbNT, B, 0, stream>>>(x, W, y, N);
    k_gather <<<nbNT, B, 0, stream>>>(rowp, cnt, csr, dinv, y,  b, h1,  N, 0);
    k_gather <<<nbNT, B, 0, stream>>>(rowp, cnt, csr, dinv, h1, b, out, N, 1);
}